// Round 13
// baseline (581.323 us; speedup 1.0000x reference)
//
#include <hip/hip_runtime.h>
#include <hip/hip_bf16.h>

typedef unsigned short u16;
typedef __attribute__((ext_vector_type(8))) short short8x;
typedef __attribute__((ext_vector_type(4))) unsigned short ushort4x;
typedef __attribute__((ext_vector_type(4))) float f32x4;
typedef __attribute__((ext_vector_type(2))) float f32x2;

__device__ __forceinline__ float bf2f(u16 u){
    unsigned int v = ((unsigned int)u) << 16;
    return __builtin_bit_cast(float, v);
}
__device__ __forceinline__ u16 f2bf(float f){
    __hip_bfloat16 h = __float2bfloat16(f);
    return __builtin_bit_cast(unsigned short, h);
}

// ---- d_ws layout (bytes 0..268288) ----
// u16[0..16384)      qw bf16   [4][64][64]
// u16[16384..32768)  kw bf16
// u16[32768..49152)  vw bf16
// u16[49152..114688) pw bf16   [256][256]
// f32[57344..64512)  dw padded [4][64][28]
// f32[64512..65024)  bnq folded [4][64][2] (sc,sh)
// f32[65024..65536)  bnk
// f32[65536..66048)  bnv
// f32[66048..66560)  bnd
// f32[66560..67072)  bnp [256][2]

__global__ __launch_bounds__(256)
void prep(const float* __restrict__ qw, const float* __restrict__ kw,
          const float* __restrict__ vw, const float* __restrict__ pw,
          const float* __restrict__ dww,
          const float* __restrict__ qbn, const float* __restrict__ kbn,
          const float* __restrict__ vbn, const float* __restrict__ dbn,
          const float* __restrict__ pbn, void* __restrict__ ws)
{
    u16* W16 = (u16*)ws;
    float* WF = (float*)ws;
    const int t = (int)blockIdx.x * 256 + (int)threadIdx.x;   // 65536 threads
    if (t < 16384){
        W16[t]         = f2bf(qw[t]);
        W16[16384 + t] = f2bf(kw[t]);
        W16[32768 + t] = f2bf(vw[t]);
    }
    if (t < 65536) W16[49152 + t] = f2bf(pw[t]);
    if (t < 7168){
        const int k = t % 28, hc = t / 28;
        WF[57344 + t] = (k < 25) ? dww[hc * 25 + k] : 0.f;
    }
    if (t < 256){
        const int h = t >> 6, c = t & 63, base = h * 256;
        #pragma unroll
        for (int s = 0; s < 4; ++s){
            const float* bn = (s == 0 ? qbn : s == 1 ? kbn : s == 2 ? vbn : dbn);
            const float g = bn[base + c], b = bn[base + 64 + c];
            const float m = bn[base + 128 + c], v = bn[base + 192 + c];
            const float sc = g * rsqrtf(v + 1e-5f);
            WF[64512 + s * 512 + h * 128 + c * 2]     = sc;
            WF[64512 + s * 512 + h * 128 + c * 2 + 1] = b - m * sc;
        }
    }
    if (t < 256){
        const float g = pbn[t], b = pbn[256 + t], m = pbn[512 + t], v = pbn[768 + t];
        const float sc = g * rsqrtf(v + 1e-5f);
        WF[66560 + t * 2]     = sc;
        WF[66560 + t * 2 + 1] = b - m * sc;
    }
}

// R12 core; sole change: __launch_bounds__ min-waves/EU 3 -> 4 (4 blocks/CU).
__global__ __launch_bounds__(256, 4)
void lwa_kernel(const float* __restrict__ x, const void* __restrict__ ws,
                float* __restrict__ y)
{
    const u16* W16 = (const u16*)ws;
    const float* WF = (const float*)ws;
    const u16* Wq = W16;
    const u16* Wk = W16 + 16384;
    const u16* Wv = W16 + 32768;
    const u16* Wp = W16 + 49152;

    __shared__ __align__(16) u16 A[64][72];
    __shared__ __align__(16) u16 B[64][72];
    __shared__ __align__(16) u16 C[64][72];
    __shared__ __align__(16) u16 D[64][72];

    const int tid  = (int)threadIdx.x;
    const int lane = tid & 63;
    const int wid  = tid >> 6;
    const int g    = lane >> 4;
    const int r15  = lane & 15;

    // temporally-tight XCD swizzle (round 8)
    const int hbid = (int)blockIdx.x;
    const int t    = hbid >> 3;
    const int wndw = (hbid & 7) * 512 + (t >> 3) * 8 + (t & 7);
    const int bimg = wndw >> 6;
    const int wy   = (wndw >> 3) & 7;
    const int wx   = wndw & 7;
    const size_t x_img = (size_t)bimg * (256 * 4096);
    const int pix_base = wy * 8 * 64 + wx * 8;

    // head-0 chunk -> A[tok][ch]
    {
        const int c = tid >> 2, qq = tid & 3;
        const float* xp = x + x_img + (size_t)c * 4096 + pix_base;
        #pragma unroll
        for (int rr = 0; rr < 2; ++rr){
            const int py = qq * 2 + rr;
            f32x4 r0 = *(const f32x4*)(xp + py * 64);
            f32x4 r1 = *(const f32x4*)(xp + py * 64 + 4);
            #pragma unroll
            for (int px = 0; px < 4; ++px){
                A[py * 8 + px][c]     = f2bf(r0[px]);
                A[py * 8 + 4 + px][c] = f2bf(r1[px]);
            }
        }
    }

    f32x4 pacc[4][4];
    #pragma unroll
    for (int a = 0; a < 4; ++a)
        #pragma unroll
        for (int b = 0; b < 4; ++b)
            pacc[a][b] = (f32x4){0.f, 0.f, 0.f, 0.f};

    const int o0 = wid * 16 + g * 4;
    const int an = tid >> 2, aj = tid & 3, ac0 = aj * 16;   // S3 roles
    const int cdw = tid & 63;                               // S2 role

    for (int i = 0; i < 4; ++i){
        // ---- batched loads for S1 (issued before the barrier) ----
        const int arow = (wid * 16 + r15) * 64 + g * 8;
        const short8x qa0 = *(const short8x*)(Wq + i * 4096 + arow);
        const short8x qa1 = *(const short8x*)(Wq + i * 4096 + arow + 32);
        const short8x ka0 = *(const short8x*)(Wk + i * 4096 + arow);
        const short8x ka1 = *(const short8x*)(Wk + i * 4096 + arow + 32);
        const short8x va0 = *(const short8x*)(Wv + i * 4096 + arow);
        const short8x va1 = *(const short8x*)(Wv + i * 4096 + arow + 32);
        f32x2 bq[4], bk[4], bv[4];
        #pragma unroll
        for (int r = 0; r < 4; ++r){
            bq[r] = *(const f32x2*)(WF + 64512 + i * 128 + (o0 + r) * 2);
            bk[r] = *(const f32x2*)(WF + 65024 + i * 128 + (o0 + r) * 2);
            bv[r] = *(const f32x2*)(WF + 65536 + i * 128 + (o0 + r) * 2);
        }
        __syncthreads();   // A(feat i) ready

        // ---- S1: fused q/k/v MFMA + BN ----
        #pragma unroll
        for (int tc = 0; tc < 4; ++tc){
            const short8x b0 = *(const short8x*)(&A[tc * 16 + r15][g * 8]);
            const short8x b1 = *(const short8x*)(&A[tc * 16 + r15][32 + g * 8]);
            f32x4 accq = (f32x4){0.f, 0.f, 0.f, 0.f};
            f32x4 acck = (f32x4){0.f, 0.f, 0.f, 0.f};
            f32x4 accv = (f32x4){0.f, 0.f, 0.f, 0.f};
            accq = __builtin_amdgcn_mfma_f32_16x16x32_bf16(qa0, b0, accq, 0, 0, 0);
            accq = __builtin_amdgcn_mfma_f32_16x16x32_bf16(qa1, b1, accq, 0, 0, 0);
            acck = __builtin_amdgcn_mfma_f32_16x16x32_bf16(ka0, b0, acck, 0, 0, 0);
            acck = __builtin_amdgcn_mfma_f32_16x16x32_bf16(ka1, b1, acck, 0, 0, 0);
            accv = __builtin_amdgcn_mfma_f32_16x16x32_bf16(va0, b0, accv, 0, 0, 0);
            accv = __builtin_amdgcn_mfma_f32_16x16x32_bf16(va1, b1, accv, 0, 0, 0);
            const int n2 = tc * 16 + r15;
            #pragma unroll
            for (int r = 0; r < 4; ++r){
                B[o0 + r][n2] = f2bf(accq[r] * bq[r][0] + bq[r][1]);   // q1 [ch][tok]
                C[o0 + r][n2] = f2bf(acck[r] * bk[r][0] + bk[r][1]);   // k  [ch][tok]
            }
            ushort4x pk;
            #pragma unroll
            for (int r = 0; r < 4; ++r) pk[r] = f2bf(accv[r] * bv[r][0] + bv[r][1]);
            *(ushort4x*)(&D[n2][o0]) = pk;                             // v  [tok][ch]
        }

        // ---- batched loads for S2/S3 (issued before the barrier) ----
        f32x4 dwv[7];
        {
            const float* dwb = WF + 57344 + (i * 64 + cdw) * 28;
            #pragma unroll
            for (int k = 0; k < 7; ++k) dwv[k] = *(const f32x4*)(dwb + k * 4);
        }
        const f32x2 bd = *(const f32x2*)(WF + 66048 + i * 128 + cdw * 2);
        float pre[16];
        if (i < 3){
            const int py = an >> 3, px = an & 7;
            const float* xc = x + x_img + pix_base + py * 64 + px
                            + (size_t)((i + 1) * 64 + ac0) * 4096;
            #pragma unroll
            for (int e = 0; e < 8; ++e){
                pre[e]     = xc[(size_t)e * 4096];
                pre[8 + e] = xc[(size_t)(8 + e) * 4096];
            }
        }
        __syncthreads();   // q1/k/v visible

        // ---- S2: depthwise 5x5 + BN; q1(B) -> qdw(A [tok][ch]) ----
        {
            const int w2 = wid;
            float rin[6][8];
            #pragma unroll
            for (int rr = 0; rr < 6; ++rr){
                const int ry = 2 * w2 - 2 + rr;
                if (ry >= 0 && ry < 8){
                    short8x rv = *(const short8x*)(&B[cdw][ry * 8]);
                    #pragma unroll
                    for (int e = 0; e < 8; ++e) rin[rr][e] = bf2f((u16)rv[e]);
                } else {
                    #pragma unroll
                    for (int e = 0; e < 8; ++e) rin[rr][e] = 0.f;
                }
            }
            #pragma unroll
            for (int oy = 0; oy < 2; ++oy){
                #pragma unroll
                for (int px = 0; px < 8; ++px){
                    float acc = 0.f;
                    #pragma unroll
                    for (int ky = 0; ky < 5; ++ky){
                        #pragma unroll
                        for (int kx = 0; kx < 5; ++kx){
                            const int ix = px - 2 + kx;
                            const int w5 = ky * 5 + kx;
                            if (ix >= 0 && ix < 8)
                                acc += rin[oy + ky][ix] * dwv[w5 >> 2][w5 & 3];
                        }
                    }
                    A[(2 * w2 + oy) * 8 + px][cdw] = f2bf(acc * bd[0] + bd[1]);
                }
            }
        }
        __syncthreads();   // qdw visible

        // ---- S3: attention; out -> B [tok][ch]; next feat -> A ----
        {
            const int n = an, c0 = ac0;
            short8x qb0 = *(const short8x*)(&A[n][c0]);
            short8x qb1 = *(const short8x*)(&A[n][c0 + 8]);
            short8x kb0 = *(const short8x*)(&C[n][c0]);
            short8x kb1 = *(const short8x*)(&C[n][c0 + 8]);
            short8x vb0 = *(const short8x*)(&D[n][c0]);
            short8x vb1 = *(const short8x*)(&D[n][c0 + 8]);
            float s[16];
            #pragma unroll
            for (int e = 0; e < 8; ++e){
                s[e]     = bf2f((u16)qb0[e]) * bf2f((u16)kb0[e]);
                s[8 + e] = bf2f((u16)qb1[e]) * bf2f((u16)kb1[e]);
            }
            float mx = s[0];
            #pragma unroll
            for (int e = 1; e < 16; ++e) mx = fmaxf(mx, s[e]);
            mx = fmaxf(mx, __shfl_xor(mx, 1));
            mx = fmaxf(mx, __shfl_xor(mx, 2));
            float sum = 0.f;
            #pragma unroll
            for (int e = 0; e < 16; ++e){ s[e] = __expf(s[e] - mx); sum += s[e]; }
            sum += __shfl_xor(sum, 1);
            sum += __shfl_xor(sum, 2);
            const float inv = 1.f / sum;
            float ov[16];
            #pragma unroll
            for (int e = 0; e < 8; ++e){
                ov[e]     = bf2f((u16)vb0[e]) * s[e] * inv;
                ov[8 + e] = bf2f((u16)vb1[e]) * s[8 + e] * inv;
            }
            short8x o0v, o1v;
            #pragma unroll
            for (int e = 0; e < 8; ++e){ o0v[e] = (short)f2bf(ov[e]); o1v[e] = (short)f2bf(ov[8 + e]); }
            *(short8x*)(&B[n][c0])     = o0v;
            *(short8x*)(&B[n][c0 + 8]) = o1v;
            if (i < 3){
                short8x f0v, f1v;
                #pragma unroll
                for (int e = 0; e < 8; ++e){
                    f0v[e] = (short)f2bf(pre[e]     + ov[e]);
                    f1v[e] = (short)f2bf(pre[8 + e] + ov[8 + e]);
                }
                *(short8x*)(&A[n][c0])     = f0v;
                *(short8x*)(&A[n][c0 + 8]) = f1v;
            }
        }

        // ---- batched p_w fragment loads for S4 (before barrier) ----
        short8x pf[8];
        #pragma unroll
        for (int rt = 0; rt < 4; ++rt)
            #pragma unroll
            for (int kk = 0; kk < 2; ++kk)
                pf[rt * 2 + kk] = *(const short8x*)(Wp + (size_t)(wid * 64 + rt * 16 + r15) * 256
                                                    + i * 64 + kk * 32 + g * 8);
        __syncthreads();   // out(B) visible

        // ---- S4: projection pacc += p_w[:, 64i:64i+64] @ B^T ----
        #pragma unroll
        for (int rt = 0; rt < 4; ++rt){
            #pragma unroll
            for (int kk = 0; kk < 2; ++kk){
                #pragma unroll
                for (int tc = 0; tc < 4; ++tc){
                    short8x b = *(const short8x*)(&B[tc * 16 + r15][kk * 32 + g * 8]);
                    pacc[rt][tc] = __builtin_amdgcn_mfma_f32_16x16x32_bf16(pf[rt * 2 + kk], b,
                                                                           pacc[rt][tc], 0, 0, 0);
                }
            }
        }
    }

    // ---- epilogue: folded projection BN + window-reverse fp32 store ----
    #pragma unroll
    for (int rt = 0; rt < 4; ++rt){
        f32x2 bp[4];
        #pragma unroll
        for (int r = 0; r < 4; ++r)
            bp[r] = *(const f32x2*)(WF + 66560 + (wid * 64 + rt * 16 + g * 4 + r) * 2);
        #pragma unroll
        for (int tc = 0; tc < 4; ++tc){
            #pragma unroll
            for (int r = 0; r < 4; ++r){
                const int o = wid * 64 + rt * 16 + g * 4 + r;
                const int n = tc * 16 + r15;
                const int py = n >> 3, px = n & 7;
                y[x_img + (size_t)o * 4096 + pix_base + py * 64 + px]
                    = pacc[rt][tc][r] * bp[r][0] + bp[r][1];
            }
        }
    }
}

extern "C" void kernel_launch(void* const* d_in, const int* in_sizes, int n_in,
                              void* d_out, int out_size, void* d_ws, size_t ws_size,
                              hipStream_t stream) {
    const float* x    = (const float*)d_in[0];
    const float* q_w  = (const float*)d_in[1];
    const float* q_bn = (const float*)d_in[2];
    const float* k_w  = (const float*)d_in[3];
    const float* k_bn = (const float*)d_in[4];
    const float* v_w  = (const float*)d_in[5];
    const float* v_bn = (const float*)d_in[6];
    const float* dw_w = (const float*)d_in[7];
    const float* dw_bn= (const float*)d_in[8];
    const float* p_w  = (const float*)d_in[9];
    const float* p_bn = (const float*)d_in[10];
    float* yout = (float*)d_out;

    prep<<<dim3(256), dim3(256), 0, stream>>>(q_w, k_w, v_w, p_w, dw_w,
                                              q_bn, k_bn, v_bn, dw_bn, p_bn, d_ws);
    lwa_kernel<<<dim3(4096), dim3(256), 0, stream>>>(x, d_ws, yout);
}

// Round 14
// 496.731 us; speedup vs baseline: 1.1703x; 1.1703x over previous
//
#include <hip/hip_runtime.h>
#include <hip/hip_bf16.h>

typedef unsigned short u16;
typedef __attribute__((ext_vector_type(8))) short short8x;
typedef __attribute__((ext_vector_type(4))) unsigned short ushort4x;
typedef __attribute__((ext_vector_type(4))) float f32x4;
typedef __attribute__((ext_vector_type(2))) float f32x2;

__device__ __forceinline__ float bf2f(u16 u){
    unsigned int v = ((unsigned int)u) << 16;
    return __builtin_bit_cast(float, v);
}
__device__ __forceinline__ u16 f2bf(float f){
    __hip_bfloat16 h = __float2bfloat16(f);
    return __builtin_bit_cast(unsigned short, h);
}

// ---- d_ws layout: identical to R12 ----
__global__ __launch_bounds__(256)
void prep(const float* __restrict__ qw, const float* __restrict__ kw,
          const float* __restrict__ vw, const float* __restrict__ pw,
          const float* __restrict__ dww,
          const float* __restrict__ qbn, const float* __restrict__ kbn,
          const float* __restrict__ vbn, const float* __restrict__ dbn,
          const float* __restrict__ pbn, void* __restrict__ ws)
{
    u16* W16 = (u16*)ws;
    float* WF = (float*)ws;
    const int t = (int)blockIdx.x * 256 + (int)threadIdx.x;
    if (t < 16384){
        W16[t]         = f2bf(qw[t]);
        W16[16384 + t] = f2bf(kw[t]);
        W16[32768 + t] = f2bf(vw[t]);
    }
    if (t < 65536) W16[49152 + t] = f2bf(pw[t]);
    if (t < 7168){
        const int k = t % 28, hc = t / 28;
        WF[57344 + t] = (k < 25) ? dww[hc * 25 + k] : 0.f;
    }
    if (t < 256){
        const int h = t >> 6, c = t & 63, base = h * 256;
        #pragma unroll
        for (int s = 0; s < 4; ++s){
            const float* bn = (s == 0 ? qbn : s == 1 ? kbn : s == 2 ? vbn : dbn);
            const float g = bn[base + c], b = bn[base + 64 + c];
            const float m = bn[base + 128 + c], v = bn[base + 192 + c];
            const float sc = g * rsqrtf(v + 1e-5f);
            WF[64512 + s * 512 + h * 128 + c * 2]     = sc;
            WF[64512 + s * 512 + h * 128 + c * 2 + 1] = b - m * sc;
        }
    }
    if (t < 256){
        const float g = pbn[t], b = pbn[256 + t], m = pbn[512 + t], v = pbn[768 + t];
        const float sc = g * rsqrtf(v + 1e-5f);
        WF[66560 + t * 2]     = sc;
        WF[66560 + t * 2 + 1] = b - m * sc;
    }
}

// R12 core, (256,3) restored; S2 merged into S1's phase (wave-local dwconv),
// qdw in swizzled E buffer. 3 barriers/head.
__global__ __launch_bounds__(256, 3)
void lwa_kernel(const float* __restrict__ x, const void* __restrict__ ws,
                float* __restrict__ y)
{
    const u16* W16 = (const u16*)ws;
    const float* WF = (const float*)ws;
    const u16* Wq = W16;
    const u16* Wk = W16 + 16384;
    const u16* Wv = W16 + 32768;
    const u16* Wp = W16 + 49152;

    __shared__ __align__(16) u16 A[64][72];   // feat [tok][ch]
    __shared__ __align__(16) u16 B[64][72];   // q1 [ch][tok] -> out [tok][ch]
    __shared__ __align__(16) u16 C[64][72];   // k  [ch][tok]
    __shared__ __align__(16) u16 D[64][72];   // v  [tok][ch]
    __shared__ __align__(16) u16 E[64][72];   // qdw [tok][ch], XOR-swizzled
    u16* E0 = &E[0][0];

    const int tid  = (int)threadIdx.x;
    const int lane = tid & 63;
    const int wid  = tid >> 6;
    const int g    = lane >> 4;
    const int r15  = lane & 15;

    // temporally-tight XCD swizzle (round 8)
    const int hbid = (int)blockIdx.x;
    const int t    = hbid >> 3;
    const int wndw = (hbid & 7) * 512 + (t >> 3) * 8 + (t & 7);
    const int bimg = wndw >> 6;
    const int wy   = (wndw >> 3) & 7;
    const int wx   = wndw & 7;
    const size_t x_img = (size_t)bimg * (256 * 4096);
    const int pix_base = wy * 8 * 64 + wx * 8;

    // head-0 chunk -> A[tok][ch]
    {
        const int c = tid >> 2, qq = tid & 3;
        const float* xp = x + x_img + (size_t)c * 4096 + pix_base;
        #pragma unroll
        for (int rr = 0; rr < 2; ++rr){
            const int py = qq * 2 + rr;
            f32x4 r0 = *(const f32x4*)(xp + py * 64);
            f32x4 r1 = *(const f32x4*)(xp + py * 64 + 4);
            #pragma unroll
            for (int px = 0; px < 4; ++px){
                A[py * 8 + px][c]     = f2bf(r0[px]);
                A[py * 8 + 4 + px][c] = f2bf(r1[px]);
            }
        }
    }

    f32x4 pacc[4][4];
    #pragma unroll
    for (int a = 0; a < 4; ++a)
        #pragma unroll
        for (int b = 0; b < 4; ++b)
            pacc[a][b] = (f32x4){0.f, 0.f, 0.f, 0.f};

    const int o0  = wid * 16 + g * 4;
    const int an  = tid >> 2, aj = tid & 3, ac0 = aj * 16;    // S3 roles
    const int cdw = wid * 16 + (lane & 15);                   // merged-S2 channel (wave-local)
    const int rp  = lane >> 4;                                // merged-S2 row pair

    for (int i = 0; i < 4; ++i){
        // ---- hoisted loads: S1 weights/BN + S2 taps/BN ----
        const int arow = (wid * 16 + r15) * 64 + g * 8;
        const short8x qa0 = *(const short8x*)(Wq + i * 4096 + arow);
        const short8x qa1 = *(const short8x*)(Wq + i * 4096 + arow + 32);
        const short8x ka0 = *(const short8x*)(Wk + i * 4096 + arow);
        const short8x ka1 = *(const short8x*)(Wk + i * 4096 + arow + 32);
        const short8x va0 = *(const short8x*)(Wv + i * 4096 + arow);
        const short8x va1 = *(const short8x*)(Wv + i * 4096 + arow + 32);
        f32x2 bq[4], bk[4], bv[4];
        #pragma unroll
        for (int r = 0; r < 4; ++r){
            bq[r] = *(const f32x2*)(WF + 64512 + i * 128 + (o0 + r) * 2);
            bk[r] = *(const f32x2*)(WF + 65024 + i * 128 + (o0 + r) * 2);
            bv[r] = *(const f32x2*)(WF + 65536 + i * 128 + (o0 + r) * 2);
        }
        f32x4 dwv[7];
        {
            const float* dwb = WF + 57344 + (i * 64 + cdw) * 28;
            #pragma unroll
            for (int k = 0; k < 7; ++k) dwv[k] = *(const f32x4*)(dwb + k * 4);
        }
        const f32x2 bd = *(const f32x2*)(WF + 66048 + i * 128 + cdw * 2);
        __syncthreads();   // (1) A(feat i) ready; B/C/D/E free

        // ---- S1: fused q/k/v MFMA + BN ----
        #pragma unroll
        for (int tc = 0; tc < 4; ++tc){
            const short8x b0 = *(const short8x*)(&A[tc * 16 + r15][g * 8]);
            const short8x b1 = *(const short8x*)(&A[tc * 16 + r15][32 + g * 8]);
            f32x4 accq = (f32x4){0.f, 0.f, 0.f, 0.f};
            f32x4 acck = (f32x4){0.f, 0.f, 0.f, 0.f};
            f32x4 accv = (f32x4){0.f, 0.f, 0.f, 0.f};
            accq = __builtin_amdgcn_mfma_f32_16x16x32_bf16(qa0, b0, accq, 0, 0, 0);
            accq = __builtin_amdgcn_mfma_f32_16x16x32_bf16(qa1, b1, accq, 0, 0, 0);
            acck = __builtin_amdgcn_mfma_f32_16x16x32_bf16(ka0, b0, acck, 0, 0, 0);
            acck = __builtin_amdgcn_mfma_f32_16x16x32_bf16(ka1, b1, acck, 0, 0, 0);
            accv = __builtin_amdgcn_mfma_f32_16x16x32_bf16(va0, b0, accv, 0, 0, 0);
            accv = __builtin_amdgcn_mfma_f32_16x16x32_bf16(va1, b1, accv, 0, 0, 0);
            const int n2 = tc * 16 + r15;
            #pragma unroll
            for (int r = 0; r < 4; ++r){
                B[o0 + r][n2] = f2bf(accq[r] * bq[r][0] + bq[r][1]);   // q1 [ch][tok]
                C[o0 + r][n2] = f2bf(acck[r] * bk[r][0] + bk[r][1]);   // k  [ch][tok]
            }
            ushort4x pk;
            #pragma unroll
            for (int r = 0; r < 4; ++r) pk[r] = f2bf(accv[r] * bv[r][0] + bv[r][1]);
            *(ushort4x*)(&D[n2][o0]) = pk;                             // v  [tok][ch]
        }

        // ---- S2 (same phase, wave-local): dwconv 5x5 + BN on this wave's channels ----
        // wave wid wrote q1 rows [16*wid,16*wid+16) in S1; read them back (in-wave
        // lgkmcnt ordering, no barrier) and write qdw -> E [tok][ch] swizzled.
        {
            float rin[6][8];
            #pragma unroll
            for (int rr = 0; rr < 6; ++rr){
                const int ry = 2 * rp - 2 + rr;
                if (ry >= 0 && ry < 8){
                    short8x rv = *(const short8x*)(&B[cdw][ry * 8]);
                    #pragma unroll
                    for (int e = 0; e < 8; ++e) rin[rr][e] = bf2f((u16)rv[e]);
                } else {
                    #pragma unroll
                    for (int e = 0; e < 8; ++e) rin[rr][e] = 0.f;
                }
            }
            #pragma unroll
            for (int oy = 0; oy < 2; ++oy){
                const int py = 2 * rp + oy;
                #pragma unroll
                for (int px = 0; px < 8; ++px){
                    float acc = 0.f;
                    #pragma unroll
                    for (int ky = 0; ky < 5; ++ky){
                        #pragma unroll
                        for (int kx = 0; kx < 5; ++kx){
                            const int ix = px - 2 + kx;
                            const int w5 = ky * 5 + kx;
                            if (ix >= 0 && ix < 8)
                                acc += rin[oy + ky][ix] * dwv[w5 >> 2][w5 & 3];
                        }
                    }
                    const int idx = ((py * 8 + px) * 72 + cdw) ^ (py << 3);
                    E0[idx] = f2bf(acc * bd[0] + bd[1]);
                }
            }
        }

        // ---- hoisted cascade x loads (drain at barrier 2) ----
        float pre[16];
        if (i < 3){
            const int py = an >> 3, px = an & 7;
            const float* xc = x + x_img + pix_base + py * 64 + px
                            + (size_t)((i + 1) * 64 + ac0) * 4096;
            #pragma unroll
            for (int e = 0; e < 8; ++e){
                pre[e]     = xc[(size_t)e * 4096];
                pre[8 + e] = xc[(size_t)(8 + e) * 4096];
            }
        }
        __syncthreads();   // (2) E(qdw)/C/D ready

        // ---- S3: attention; out -> B [tok][ch]; next feat -> A ----
        {
            const int n = an, c0 = ac0;
            const int sw = ((n >> 3) & 7) << 3;
            const short8x qb0 = *(const short8x*)(E0 + (((n * 72) + c0) ^ sw));
            const short8x qb1 = *(const short8x*)(E0 + (((n * 72) + c0 + 8) ^ sw));
            short8x kb0 = *(const short8x*)(&C[n][c0]);
            short8x kb1 = *(const short8x*)(&C[n][c0 + 8]);
            short8x vb0 = *(const short8x*)(&D[n][c0]);
            short8x vb1 = *(const short8x*)(&D[n][c0 + 8]);
            float s[16];
            #pragma unroll
            for (int e = 0; e < 8; ++e){
                s[e]     = bf2f((u16)qb0[e]) * bf2f((u16)kb0[e]);
                s[8 + e] = bf2f((u16)qb1[e]) * bf2f((u16)kb1[e]);
            }
            float mx = s[0];
            #pragma unroll
            for (int e = 1; e < 16; ++e) mx = fmaxf(mx, s[e]);
            mx = fmaxf(mx, __shfl_xor(mx, 1));
            mx = fmaxf(mx, __shfl_xor(mx, 2));
            float sum = 0.f;
            #pragma unroll
            for (int e = 0; e < 16; ++e){ s[e] = __expf(s[e] - mx); sum += s[e]; }
            sum += __shfl_xor(sum, 1);
            sum += __shfl_xor(sum, 2);
            const float inv = 1.f / sum;
            float ov[16];
            #pragma unroll
            for (int e = 0; e < 8; ++e){
                ov[e]     = bf2f((u16)vb0[e]) * s[e] * inv;
                ov[8 + e] = bf2f((u16)vb1[e]) * s[8 + e] * inv;
            }
            short8x o0v, o1v;
            #pragma unroll
            for (int e = 0; e < 8; ++e){ o0v[e] = (short)f2bf(ov[e]); o1v[e] = (short)f2bf(ov[8 + e]); }
            *(short8x*)(&B[n][c0])     = o0v;
            *(short8x*)(&B[n][c0 + 8]) = o1v;
            if (i < 3){
                short8x f0v, f1v;
                #pragma unroll
                for (int e = 0; e < 8; ++e){
                    f0v[e] = (short)f2bf(pre[e]     + ov[e]);
                    f1v[e] = (short)f2bf(pre[8 + e] + ov[8 + e]);
                }
                *(short8x*)(&A[n][c0])     = f0v;
                *(short8x*)(&A[n][c0 + 8]) = f1v;
            }
        }

        // ---- hoisted p_w fragments (drain at barrier 3) ----
        short8x pf[8];
        #pragma unroll
        for (int rt = 0; rt < 4; ++rt)
            #pragma unroll
            for (int kk = 0; kk < 2; ++kk)
                pf[rt * 2 + kk] = *(const short8x*)(Wp + (size_t)(wid * 64 + rt * 16 + r15) * 256
                                                    + i * 64 + kk * 32 + g * 8);
        __syncthreads();   // (3) B(out) ready

        // ---- S4: projection pacc += p_w[:, 64i:64i+64] @ B^T ----
        #pragma unroll
        for (int rt = 0; rt < 4; ++rt){
            #pragma unroll
            for (int kk = 0; kk < 2; ++kk){
                #pragma unroll
                for (int tc = 0; tc < 4; ++tc){
                    short8x b = *(const short8x*)(&B[tc * 16 + r15][kk * 32 + g * 8]);
                    pacc[rt][tc] = __builtin_amdgcn_mfma_f32_16x16x32_bf16(pf[rt * 2 + kk], b,
                                                                           pacc[rt][tc], 0, 0, 0);
                }
            }
        }
    }

    // ---- epilogue: folded projection BN + window-reverse fp32 store ----
    #pragma unroll
    for (int rt = 0; rt < 4; ++rt){
        f32x2 bp[4];
        #pragma unroll
        for (int r = 0; r < 4; ++r)
            bp[r] = *(const f32x2*)(WF + 66560 + (wid * 64 + rt * 16 + g * 4 + r) * 2);
        #pragma unroll
        for (int tc = 0; tc < 4; ++tc){
            #pragma unroll
            for (int r = 0; r < 4; ++r){
                const int o = wid * 64 + rt * 16 + g * 4 + r;
                const int n = tc * 16 + r15;
                const int py = n >> 3, px = n & 7;
                y[x_img + (size_t)o * 4096 + pix_base + py * 64 + px]
                    = pacc[rt][tc][r] * bp[r][0] + bp[r][1];
            }
        }
    }
}

extern "C" void kernel_launch(void* const* d_in, const int* in_sizes, int n_in,
                              void* d_out, int out_size, void* d_ws, size_t ws_size,
                              hipStream_t stream) {
    const float* x    = (const float*)d_in[0];
    const float* q_w  = (const float*)d_in[1];
    const float* q_bn = (const float*)d_in[2];
    const float* k_w  = (const float*)d_in[3];
    const float* k_bn = (const float*)d_in[4];
    const float* v_w  = (const float*)d_in[5];
    const float* v_bn = (const float*)d_in[6];
    const float* dw_w = (const float*)d_in[7];
    const float* dw_bn= (const float*)d_in[8];
    const float* p_w  = (const float*)d_in[9];
    const float* p_bn = (const float*)d_in[10];
    float* yout = (float*)d_out;

    prep<<<dim3(256), dim3(256), 0, stream>>>(q_w, k_w, v_w, p_w, dw_w,
                                              q_bn, k_bn, v_bn, dw_bn, p_bn, d_ws);
    lwa_kernel<<<dim3(4096), dim3(256), 0, stream>>>(x, d_ws, yout);
}

// Round 15
// 356.385 us; speedup vs baseline: 1.6312x; 1.3938x over previous
//
#include <hip/hip_runtime.h>
#include <hip/hip_bf16.h>

typedef unsigned short u16;
typedef __attribute__((ext_vector_type(8))) short short8x;
typedef __attribute__((ext_vector_type(4))) unsigned short ushort4x;
typedef __attribute__((ext_vector_type(4))) float f32x4;
typedef __attribute__((ext_vector_type(2))) float f32x2;

__device__ __forceinline__ float bf2f(u16 u){
    unsigned int v = ((unsigned int)u) << 16;
    return __builtin_bit_cast(float, v);
}
__device__ __forceinline__ u16 f2bf(float f){
    __hip_bfloat16 h = __float2bfloat16(f);
    return __builtin_bit_cast(unsigned short, h);
}
// Barrier that drains ONLY LDS ops (lgkmcnt), leaving global loads in flight
// (T4: never vmcnt(0) at a barrier). All cross-wave data in this kernel moves
// through LDS; globals are read-only until the epilogue -> this is sufficient.
__device__ __forceinline__ void lds_barrier(){
    asm volatile("s_waitcnt lgkmcnt(0)" ::: "memory");
    __builtin_amdgcn_s_barrier();
}

// ---- d_ws layout: identical to R12 ----
__global__ __launch_bounds__(256)
void prep(const float* __restrict__ qw, const float* __restrict__ kw,
          const float* __restrict__ vw, const float* __restrict__ pw,
          const float* __restrict__ dww,
          const float* __restrict__ qbn, const float* __restrict__ kbn,
          const float* __restrict__ vbn, const float* __restrict__ dbn,
          const float* __restrict__ pbn, void* __restrict__ ws)
{
    u16* W16 = (u16*)ws;
    float* WF = (float*)ws;
    const int t = (int)blockIdx.x * 256 + (int)threadIdx.x;
    if (t < 16384){
        W16[t]         = f2bf(qw[t]);
        W16[16384 + t] = f2bf(kw[t]);
        W16[32768 + t] = f2bf(vw[t]);
    }
    if (t < 65536) W16[49152 + t] = f2bf(pw[t]);
    if (t < 7168){
        const int k = t % 28, hc = t / 28;
        WF[57344 + t] = (k < 25) ? dww[hc * 25 + k] : 0.f;
    }
    if (t < 256){
        const int h = t >> 6, c = t & 63, base = h * 256;
        #pragma unroll
        for (int s = 0; s < 4; ++s){
            const float* bn = (s == 0 ? qbn : s == 1 ? kbn : s == 2 ? vbn : dbn);
            const float g = bn[base + c], b = bn[base + 64 + c];
            const float m = bn[base + 128 + c], v = bn[base + 192 + c];
            const float sc = g * rsqrtf(v + 1e-5f);
            WF[64512 + s * 512 + h * 128 + c * 2]     = sc;
            WF[64512 + s * 512 + h * 128 + c * 2 + 1] = b - m * sc;
        }
    }
    if (t < 256){
        const float g = pbn[t], b = pbn[256 + t], m = pbn[512 + t], v = pbn[768 + t];
        const float sc = g * rsqrtf(v + 1e-5f);
        WF[66560 + t * 2]     = sc;
        WF[66560 + t * 2 + 1] = b - m * sc;
    }
}

// Exact R12 core; sole change: in-loop __syncthreads() -> lds_barrier().
__global__ __launch_bounds__(256, 3)
void lwa_kernel(const float* __restrict__ x, const void* __restrict__ ws,
                float* __restrict__ y)
{
    const u16* W16 = (const u16*)ws;
    const float* WF = (const float*)ws;
    const u16* Wq = W16;
    const u16* Wk = W16 + 16384;
    const u16* Wv = W16 + 32768;
    const u16* Wp = W16 + 49152;

    __shared__ __align__(16) u16 A[64][72];
    __shared__ __align__(16) u16 B[64][72];
    __shared__ __align__(16) u16 C[64][72];
    __shared__ __align__(16) u16 D[64][72];

    const int tid  = (int)threadIdx.x;
    const int lane = tid & 63;
    const int wid  = tid >> 6;
    const int g    = lane >> 4;
    const int r15  = lane & 15;

    // temporally-tight XCD swizzle (round 8)
    const int hbid = (int)blockIdx.x;
    const int t    = hbid >> 3;
    const int wndw = (hbid & 7) * 512 + (t >> 3) * 8 + (t & 7);
    const int bimg = wndw >> 6;
    const int wy   = (wndw >> 3) & 7;
    const int wx   = wndw & 7;
    const size_t x_img = (size_t)bimg * (256 * 4096);
    const int pix_base = wy * 8 * 64 + wx * 8;

    // head-0 chunk -> A[tok][ch]
    {
        const int c = tid >> 2, qq = tid & 3;
        const float* xp = x + x_img + (size_t)c * 4096 + pix_base;
        #pragma unroll
        for (int rr = 0; rr < 2; ++rr){
            const int py = qq * 2 + rr;
            f32x4 r0 = *(const f32x4*)(xp + py * 64);
            f32x4 r1 = *(const f32x4*)(xp + py * 64 + 4);
            #pragma unroll
            for (int px = 0; px < 4; ++px){
                A[py * 8 + px][c]     = f2bf(r0[px]);
                A[py * 8 + 4 + px][c] = f2bf(r1[px]);
            }
        }
    }

    f32x4 pacc[4][4];
    #pragma unroll
    for (int a = 0; a < 4; ++a)
        #pragma unroll
        for (int b = 0; b < 4; ++b)
            pacc[a][b] = (f32x4){0.f, 0.f, 0.f, 0.f};

    const int o0 = wid * 16 + g * 4;
    const int an = tid >> 2, aj = tid & 3, ac0 = aj * 16;   // S3 roles
    const int cdw = tid & 63;                               // S2 role

    for (int i = 0; i < 4; ++i){
        // ---- batched loads for S1 (issued before the barrier, stay in flight) ----
        const int arow = (wid * 16 + r15) * 64 + g * 8;
        const short8x qa0 = *(const short8x*)(Wq + i * 4096 + arow);
        const short8x qa1 = *(const short8x*)(Wq + i * 4096 + arow + 32);
        const short8x ka0 = *(const short8x*)(Wk + i * 4096 + arow);
        const short8x ka1 = *(const short8x*)(Wk + i * 4096 + arow + 32);
        const short8x va0 = *(const short8x*)(Wv + i * 4096 + arow);
        const short8x va1 = *(const short8x*)(Wv + i * 4096 + arow + 32);
        f32x2 bq[4], bk[4], bv[4];
        #pragma unroll
        for (int r = 0; r < 4; ++r){
            bq[r] = *(const f32x2*)(WF + 64512 + i * 128 + (o0 + r) * 2);
            bk[r] = *(const f32x2*)(WF + 65024 + i * 128 + (o0 + r) * 2);
            bv[r] = *(const f32x2*)(WF + 65536 + i * 128 + (o0 + r) * 2);
        }
        lds_barrier();   // (1) A(feat i) ready

        // ---- S1: fused q/k/v MFMA + BN ----
        #pragma unroll
        for (int tc = 0; tc < 4; ++tc){
            const short8x b0 = *(const short8x*)(&A[tc * 16 + r15][g * 8]);
            const short8x b1 = *(const short8x*)(&A[tc * 16 + r15][32 + g * 8]);
            f32x4 accq = (f32x4){0.f, 0.f, 0.f, 0.f};
            f32x4 acck = (f32x4){0.f, 0.f, 0.f, 0.f};
            f32x4 accv = (f32x4){0.f, 0.f, 0.f, 0.f};
            accq = __builtin_amdgcn_mfma_f32_16x16x32_bf16(qa0, b0, accq, 0, 0, 0);
            accq = __builtin_amdgcn_mfma_f32_16x16x32_bf16(qa1, b1, accq, 0, 0, 0);
            acck = __builtin_amdgcn_mfma_f32_16x16x32_bf16(ka0, b0, acck, 0, 0, 0);
            acck = __builtin_amdgcn_mfma_f32_16x16x32_bf16(ka1, b1, acck, 0, 0, 0);
            accv = __builtin_amdgcn_mfma_f32_16x16x32_bf16(va0, b0, accv, 0, 0, 0);
            accv = __builtin_amdgcn_mfma_f32_16x16x32_bf16(va1, b1, accv, 0, 0, 0);
            const int n2 = tc * 16 + r15;
            #pragma unroll
            for (int r = 0; r < 4; ++r){
                B[o0 + r][n2] = f2bf(accq[r] * bq[r][0] + bq[r][1]);   // q1 [ch][tok]
                C[o0 + r][n2] = f2bf(acck[r] * bk[r][0] + bk[r][1]);   // k  [ch][tok]
            }
            ushort4x pk;
            #pragma unroll
            for (int r = 0; r < 4; ++r) pk[r] = f2bf(accv[r] * bv[r][0] + bv[r][1]);
            *(ushort4x*)(&D[n2][o0]) = pk;                             // v  [tok][ch]
        }

        // ---- batched loads for S2/S3 (issued before the barrier, stay in flight) ----
        f32x4 dwv[7];
        {
            const float* dwb = WF + 57344 + (i * 64 + cdw) * 28;
            #pragma unroll
            for (int k = 0; k < 7; ++k) dwv[k] = *(const f32x4*)(dwb + k * 4);
        }
        const f32x2 bd = *(const f32x2*)(WF + 66048 + i * 128 + cdw * 2);
        float pre[16];
        if (i < 3){
            const int py = an >> 3, px = an & 7;
            const float* xc = x + x_img + pix_base + py * 64 + px
                            + (size_t)((i + 1) * 64 + ac0) * 4096;
            #pragma unroll
            for (int e = 0; e < 8; ++e){
                pre[e]     = xc[(size_t)e * 4096];
                pre[8 + e] = xc[(size_t)(8 + e) * 4096];
            }
        }
        lds_barrier();   // (2) q1/k/v visible

        // ---- S2: depthwise 5x5 + BN; q1(B) -> qdw(A [tok][ch]) ----
        {
            const int w2 = wid;
            float rin[6][8];
            #pragma unroll
            for (int rr = 0; rr < 6; ++rr){
                const int ry = 2 * w2 - 2 + rr;
                if (ry >= 0 && ry < 8){
                    short8x rv = *(const short8x*)(&B[cdw][ry * 8]);
                    #pragma unroll
                    for (int e = 0; e < 8; ++e) rin[rr][e] = bf2f((u16)rv[e]);
                } else {
                    #pragma unroll
                    for (int e = 0; e < 8; ++e) rin[rr][e] = 0.f;
                }
            }
            #pragma unroll
            for (int oy = 0; oy < 2; ++oy){
                #pragma unroll
                for (int px = 0; px < 8; ++px){
                    float acc = 0.f;
                    #pragma unroll
                    for (int ky = 0; ky < 5; ++ky){
                        #pragma unroll
                        for (int kx = 0; kx < 5; ++kx){
                            const int ix = px - 2 + kx;
                            const int w5 = ky * 5 + kx;
                            if (ix >= 0 && ix < 8)
                                acc += rin[oy + ky][ix] * dwv[w5 >> 2][w5 & 3];
                        }
                    }
                    A[(2 * w2 + oy) * 8 + px][cdw] = f2bf(acc * bd[0] + bd[1]);
                }
            }
        }
        lds_barrier();   // (3) qdw visible

        // ---- S3: attention; out -> B [tok][ch]; next feat -> A ----
        {
            const int n = an, c0 = ac0;
            short8x qb0 = *(const short8x*)(&A[n][c0]);
            short8x qb1 = *(const short8x*)(&A[n][c0 + 8]);
            short8x kb0 = *(const short8x*)(&C[n][c0]);
            short8x kb1 = *(const short8x*)(&C[n][c0 + 8]);
            short8x vb0 = *(const short8x*)(&D[n][c0]);
            short8x vb1 = *(const short8x*)(&D[n][c0 + 8]);
            float s[16];
            #pragma unroll
            for (int e = 0; e < 8; ++e){
                s[e]     = bf2f((u16)qb0[e]) * bf2f((u16)kb0[e]);
                s[8 + e] = bf2f((u16)qb1[e]) * bf2f((u16)kb1[e]);
            }
            float mx = s[0];
            #pragma unroll
            for (int e = 1; e < 16; ++e) mx = fmaxf(mx, s[e]);
            mx = fmaxf(mx, __shfl_xor(mx, 1));
            mx = fmaxf(mx, __shfl_xor(mx, 2));
            float sum = 0.f;
            #pragma unroll
            for (int e = 0; e < 16; ++e){ s[e] = __expf(s[e] - mx); sum += s[e]; }
            sum += __shfl_xor(sum, 1);
            sum += __shfl_xor(sum, 2);
            const float inv = 1.f / sum;
            float ov[16];
            #pragma unroll
            for (int e = 0; e < 8; ++e){
                ov[e]     = bf2f((u16)vb0[e]) * s[e] * inv;
                ov[8 + e] = bf2f((u16)vb1[e]) * s[8 + e] * inv;
            }
            short8x o0v, o1v;
            #pragma unroll
            for (int e = 0; e < 8; ++e){ o0v[e] = (short)f2bf(ov[e]); o1v[e] = (short)f2bf(ov[8 + e]); }
            *(short8x*)(&B[n][c0])     = o0v;
            *(short8x*)(&B[n][c0 + 8]) = o1v;
            if (i < 3){
                short8x f0v, f1v;
                #pragma unroll
                for (int e = 0; e < 8; ++e){
                    f0v[e] = (short)f2bf(pre[e]     + ov[e]);
                    f1v[e] = (short)f2bf(pre[8 + e] + ov[8 + e]);
                }
                *(short8x*)(&A[n][c0])     = f0v;
                *(short8x*)(&A[n][c0 + 8]) = f1v;
            }
        }

        // ---- batched p_w fragment loads for S4 (before barrier, stay in flight) ----
        short8x pf[8];
        #pragma unroll
        for (int rt = 0; rt < 4; ++rt)
            #pragma unroll
            for (int kk = 0; kk < 2; ++kk)
                pf[rt * 2 + kk] = *(const short8x*)(Wp + (size_t)(wid * 64 + rt * 16 + r15) * 256
                                                    + i * 64 + kk * 32 + g * 8);
        lds_barrier();   // (4) out(B) visible

        // ---- S4: projection pacc += p_w[:, 64i:64i+64] @ B^T ----
        #pragma unroll
        for (int rt = 0; rt < 4; ++rt){
            #pragma unroll
            for (int kk = 0; kk < 2; ++kk){
                #pragma unroll
                for (int tc = 0; tc < 4; ++tc){
                    short8x b = *(const short8x*)(&B[tc * 16 + r15][kk * 32 + g * 8]);
                    pacc[rt][tc] = __builtin_amdgcn_mfma_f32_16x16x32_bf16(pf[rt * 2 + kk], b,
                                                                           pacc[rt][tc], 0, 0, 0);
                }
            }
        }
    }

    // ---- epilogue: folded projection BN + window-reverse fp32 store ----
    #pragma unroll
    for (int rt = 0; rt < 4; ++rt){
        f32x2 bp[4];
        #pragma unroll
        for (int r = 0; r < 4; ++r)
            bp[r] = *(const f32x2*)(WF + 66560 + (wid * 64 + rt * 16 + g * 4 + r) * 2);
        #pragma unroll
        for (int tc = 0; tc < 4; ++tc){
            #pragma unroll
            for (int r = 0; r < 4; ++r){
                const int o = wid * 64 + rt * 16 + g * 4 + r;
                const int n = tc * 16 + r15;
                const int py = n >> 3, px = n & 7;
                y[x_img + (size_t)o * 4096 + pix_base + py * 64 + px]
                    = pacc[rt][tc][r] * bp[r][0] + bp[r][1];
            }
        }
    }
}

extern "C" void kernel_launch(void* const* d_in, const int* in_sizes, int n_in,
                              void* d_out, int out_size, void* d_ws, size_t ws_size,
                              hipStream_t stream) {
    const float* x    = (const float*)d_in[0];
    const float* q_w  = (const float*)d_in[1];
    const float* q_bn = (const float*)d_in[2];
    const float* k_w  = (const float*)d_in[3];
    const float* k_bn = (const float*)d_in[4];
    const float* v_w  = (const float*)d_in[5];
    const float* v_bn = (const float*)d_in[6];
    const float* dw_w = (const float*)d_in[7];
    const float* dw_bn= (const float*)d_in[8];
    const float* p_w  = (const float*)d_in[9];
    const float* p_bn = (const float*)d_in[10];
    float* yout = (float*)d_out;

    prep<<<dim3(256), dim3(256), 0, stream>>>(q_w, k_w, v_w, p_w, dw_w,
                                              q_bn, k_bn, v_bn, dw_bn, p_bn, d_ws);
    lwa_kernel<<<dim3(4096), dim3(256), 0, stream>>>(x, d_ws, yout);
}